// Round 14
// baseline (282.050 us; speedup 1.0000x reference)
//
#include <hip/hip_runtime.h>
#include <hip/hip_fp16.h>

#define N_NODES 100000
#define N_EDGES 1600000
#define D 128

#define NBIN 196            // coarse bins: dst>>9, 512 nodes each
#define NCHUNK 391          // edge chunks of 4096
#define CHUNK_E 4096
#define SCAN_TOT (NBIN * NCHUNK)   // 76636
#define SC_NB ((SCAN_TOT + 1023) / 1024)   // 75

typedef __attribute__((ext_vector_type(8))) _Float16 f16x8;
typedef __attribute__((ext_vector_type(4))) float f32x4;

__device__ __forceinline__ float h2f(ushort u) {
    __half_raw r; r.x = u;
    return __half2float(__half(r));
}
__device__ __forceinline__ ushort f2h(float f) {
    __half_raw r = __half_raw(__float2half(f));
    return r.x;
}

// ---------------- P1: coarse partition (LDS histograms, no global atomics) ---------

__global__ __launch_bounds__(256) void p1_hist(const int* __restrict__ dst,
                                               int* __restrict__ blockhist) {
    __shared__ int h[NBIN];
    int tid = threadIdx.x;
    for (int b = tid; b < NBIN; b += 256) h[b] = 0;
    __syncthreads();
    int base = blockIdx.x * CHUNK_E;
#pragma unroll
    for (int j = 0; j < 16; ++j) {
        int i = base + j * 256 + tid;
        if (i < N_EDGES) atomicAdd(&h[dst[i] >> 9], 1);
    }
    __syncthreads();
    for (int b = tid; b < NBIN; b += 256)
        blockhist[b * NCHUNK + blockIdx.x] = h[b];
}

// ---- hierarchical exclusive scan of blockhist[SCAN_TOT] (in place) ----

__global__ __launch_bounds__(256) void scan_a(const int* __restrict__ bh,
                                              int* __restrict__ partials) {
    __shared__ int sums[256];
    int tid = threadIdx.x;
    int base = blockIdx.x * 1024 + tid * 4;
    int s = 0;
#pragma unroll
    for (int i = 0; i < 4; ++i) {
        int idx = base + i;
        if (idx < SCAN_TOT) s += bh[idx];
    }
    sums[tid] = s;
    __syncthreads();
#pragma unroll
    for (int off = 128; off > 0; off >>= 1) {
        if (tid < off) sums[tid] += sums[tid + off];
        __syncthreads();
    }
    if (tid == 0) partials[blockIdx.x] = sums[0];
}

__global__ __launch_bounds__(128) void scan_b(int* __restrict__ partials,
                                              int* __restrict__ row_ptr) {
    __shared__ int s[128];
    int tid = threadIdx.x;
    int v = (tid < SC_NB) ? partials[tid] : 0;
    s[tid] = v;
    __syncthreads();
    for (int off = 1; off < 128; off <<= 1) {
        int t = (tid >= off) ? s[tid - off] : 0;
        __syncthreads();
        s[tid] += t;
        __syncthreads();
    }
    if (tid < SC_NB) partials[tid] = s[tid] - v;   // exclusive block offsets
    if (tid == 0) row_ptr[N_NODES] = N_EDGES;
}

__global__ __launch_bounds__(256) void scan_c(int* __restrict__ bh,
                                              const int* __restrict__ partials) {
    __shared__ int tsum[256];
    int tid = threadIdx.x;
    int base = blockIdx.x * 1024 + tid * 4;
    int d[4];
#pragma unroll
    for (int i = 0; i < 4; ++i)
        d[i] = (base + i < SCAN_TOT) ? bh[base + i] : 0;
    int s = d[0] + d[1] + d[2] + d[3];
    tsum[tid] = s;
    __syncthreads();
    for (int off = 1; off < 256; off <<= 1) {
        int t = (tid >= off) ? tsum[tid - off] : 0;
        __syncthreads();
        tsum[tid] += t;
        __syncthreads();
    }
    int run = partials[blockIdx.x] + tsum[tid] - s;   // exclusive start
#pragma unroll
    for (int i = 0; i < 4; ++i) {
        int idx = base + i;
        if (idx < SCAN_TOT) {
            bh[idx] = run;
            run += d[i];
        }
    }
}

// record: {src | dstLocal<<17, w1h | w2h<<16}
__global__ __launch_bounds__(256) void p1_scatter(const int* __restrict__ src,
                                                  const int* __restrict__ dst,
                                                  const float* __restrict__ w1,
                                                  const float* __restrict__ w2,
                                                  const int* __restrict__ bh,
                                                  uint2* __restrict__ part) {
    __shared__ int cur[NBIN];
    int tid = threadIdx.x;
    for (int b = tid; b < NBIN; b += 256) cur[b] = bh[b * NCHUNK + blockIdx.x];
    __syncthreads();
    int base = blockIdx.x * CHUNK_E;
#pragma unroll
    for (int j = 0; j < 16; ++j) {
        int i = base + j * 256 + tid;
        if (i < N_EDGES) {
            int d = dst[i];
            int pos = atomicAdd(&cur[d >> 9], 1);
            uint2 e;
            e.x = (unsigned)src[i] | ((unsigned)(d & 511) << 17);
            e.y = (unsigned)f2h(w1[i]) | ((unsigned)f2h(w2[i]) << 16);
            part[pos] = e;
        }
    }
}

// ---------------- P2: per-bin fine grouping -> exact CSR, deg_inv folded ----------

__global__ __launch_bounds__(256) void p2_kernel(const int* __restrict__ bh,
                                                 const uint2* __restrict__ part,
                                                 int* __restrict__ row_ptr,
                                                 uint2* __restrict__ packed) {
    __shared__ int deg2[512];
    __shared__ int cur[512];
    __shared__ int sb[256];
    int tid = threadIdx.x;
    int bin = blockIdx.x;
    int base = bh[bin * NCHUNK];
    int endv = (bin == NBIN - 1) ? N_EDGES : bh[(bin + 1) * NCHUNK];
    int cnt = endv - base;
    deg2[tid] = 0; deg2[tid + 256] = 0;
    __syncthreads();
    for (int k = tid; k < cnt; k += 256)
        atomicAdd(&deg2[part[base + k].x >> 17], 1);
    __syncthreads();
    int s0 = deg2[2 * tid], s1 = deg2[2 * tid + 1];
    int ts = s0 + s1;
    sb[tid] = ts;
    __syncthreads();
    for (int off = 1; off < 256; off <<= 1) {
        int v = (tid >= off) ? sb[tid - off] : 0;
        __syncthreads();
        sb[tid] += v;
        __syncthreads();
    }
    int ex = sb[tid] - ts;                     // exclusive within bin
    cur[2 * tid] = ex;
    cur[2 * tid + 1] = ex + s0;
    int node0 = bin * 512 + 2 * tid;
    if (node0 < N_NODES)     row_ptr[node0]     = base + ex;
    if (node0 + 1 < N_NODES) row_ptr[node0 + 1] = base + ex + s0;
    __syncthreads();
    for (int k = tid; k < cnt; k += 256) {
        uint2 r = part[base + k];
        int local = r.x >> 17;
        float di = 1.0f / (float)deg2[local];
        int pos = base + atomicAdd(&cur[local], 1);
        uint2 e;
        e.x = r.x & 0x1FFFFu;
        e.y = (unsigned)f2h(h2f((ushort)(r.y & 0xFFFFu)) * di)
            | ((unsigned)f2h(h2f((ushort)(r.y >> 16)) * di) << 16);
        packed[pos] = e;
    }
}

// ---------------- fp32 -> fp16 convert (8 elems/thread) ----------------

__global__ __launch_bounds__(256) void cvt_f16_kernel(const float* __restrict__ in,
                                                      ushort* __restrict__ out) {
    long i = ((long)blockIdx.x * 256 + threadIdx.x) * 8;
    const float4 a = *reinterpret_cast<const float4*>(&in[i]);
    const float4 b = *reinterpret_cast<const float4*>(&in[i + 4]);
    ushort4 u0, u1;
    u0.x = f2h(a.x); u0.y = f2h(a.y); u0.z = f2h(a.z); u0.w = f2h(a.w);
    u1.x = f2h(b.x); u1.y = f2h(b.y); u1.z = f2h(b.z); u1.w = f2h(b.w);
    *reinterpret_cast<ushort4*>(&out[i]) = u0;
    *reinterpret_cast<ushort4*>(&out[i + 4]) = u1;
}

// ---------------- W tiling: fragment-ordered fp16 (all 3 tables, one launch) ------
// addr(k,n) = ((k>>3)*128 + n)*8 + (k&7)

__global__ __launch_bounds__(256) void wtile_all_kernel(const float* __restrict__ W1,
                                                        const float* __restrict__ W2,
                                                        const float* __restrict__ Wl1,
                                                        ushort* __restrict__ W1t,
                                                        ushort* __restrict__ W2t,
                                                        ushort* __restrict__ Wl1t) {
    int i = blockIdx.x * 256 + threadIdx.x;
    const int DD2 = 2 * D * D;
    const float* src; ushort* dstp; int j;
    if (i < DD2)               { src = W1;  dstp = W1t;  j = i; }
    else if (i < 2 * DD2)      { src = W2;  dstp = W2t;  j = i - DD2; }
    else if (i < 2 * DD2 + D * D) { src = Wl1; dstp = Wl1t; j = i - 2 * DD2; }
    else return;
    int k = j >> 7, n = j & 127;
    int addr = (((k >> 3) << 7) + n) * 8 + (k & 7);
    dstp[addr] = f2h(src[j]);
}

// ---------------- Fused SpMM + GEMM (+ classifier) ----------------
// Phase 1: wave gathers agg rows for its 16 nodes -> per-wave LDS tile (fp16).
// Phase 2: MFMA GEMM, A-frags ks<4 from global (in1), ks>=4 from LDS (agg).
// CLS=false: write h1. CLS=true: h2 -> LDS (reuse tile) -> classifier.

#define LSTR 136   // LDS row stride in shorts (2-way bank alias only)

template<int WIDX, bool CLS>
__global__ __launch_bounds__(256) void spmm_gemm_kernel(
        const ushort* __restrict__ xin,     // gather source AND in1
        const uint2* __restrict__ edges,
        const int* __restrict__ row_ptr,
        const ushort* __restrict__ Wt,
        const float* __restrict__ bias,
        ushort* __restrict__ outp,          // h1 (CLS=false)
        const ushort* __restrict__ Wl1t,    // CLS=true only
        const float* __restrict__ bl1,
        const float* __restrict__ Wl2,
        const float* __restrict__ bl2,
        float* __restrict__ outc) {
    __shared__ __align__(16) ushort lds[4][16][LSTR];
    int tid = threadIdx.x;
    int w = tid >> 6, l = tid & 63;
    int base_m = blockIdx.x * 64 + w * 16;
    const _Float16* xh = reinterpret_cast<const _Float16*>(xin);

    // ---- phase 1: gather agg for 16 nodes (whole wave per node) ----
    {
        int par = l >> 4;                  // edge parity 0..3
        int dl = l & 15;                   // dims 8*dl..8*dl+7
        for (int nn = 0; nn < 16; ++nn) {
            int n = base_m + nn; if (n >= N_NODES) n = N_NODES - 1;
            int beg = row_ptr[n], end = row_ptr[n + 1];
            float a[8] = {0.f, 0.f, 0.f, 0.f, 0.f, 0.f, 0.f, 0.f};
            int i = beg;
            for (; i + 15 < end; i += 16) {
                const uint2 e0 = edges[i + par];
                const uint2 e1 = edges[i + 4 + par];
                const uint2 e2 = edges[i + 8 + par];
                const uint2 e3 = edges[i + 12 + par];
                float w0 = (float)__builtin_bit_cast(_Float16, (ushort)(WIDX ? (e0.y >> 16) : (e0.y & 0xFFFFu)));
                float w1 = (float)__builtin_bit_cast(_Float16, (ushort)(WIDX ? (e1.y >> 16) : (e1.y & 0xFFFFu)));
                float w2 = (float)__builtin_bit_cast(_Float16, (ushort)(WIDX ? (e2.y >> 16) : (e2.y & 0xFFFFu)));
                float w3 = (float)__builtin_bit_cast(_Float16, (ushort)(WIDX ? (e3.y >> 16) : (e3.y & 0xFFFFu)));
                const f16x8 v0 = *reinterpret_cast<const f16x8*>(&xh[(long)e0.x * D + dl * 8]);
                const f16x8 v1 = *reinterpret_cast<const f16x8*>(&xh[(long)e1.x * D + dl * 8]);
                const f16x8 v2 = *reinterpret_cast<const f16x8*>(&xh[(long)e2.x * D + dl * 8]);
                const f16x8 v3 = *reinterpret_cast<const f16x8*>(&xh[(long)e3.x * D + dl * 8]);
#pragma unroll
                for (int j = 0; j < 8; ++j)
                    a[j] += (float)v0[j] * w0 + (float)v1[j] * w1
                          + (float)v2[j] * w2 + (float)v3[j] * w3;
            }
            for (; i + 7 < end; i += 8) {
                const uint2 e0 = edges[i + par];
                const uint2 e1 = edges[i + 4 + par];
                float w0 = (float)__builtin_bit_cast(_Float16, (ushort)(WIDX ? (e0.y >> 16) : (e0.y & 0xFFFFu)));
                float w1 = (float)__builtin_bit_cast(_Float16, (ushort)(WIDX ? (e1.y >> 16) : (e1.y & 0xFFFFu)));
                const f16x8 v0 = *reinterpret_cast<const f16x8*>(&xh[(long)e0.x * D + dl * 8]);
                const f16x8 v1 = *reinterpret_cast<const f16x8*>(&xh[(long)e1.x * D + dl * 8]);
#pragma unroll
                for (int j = 0; j < 8; ++j)
                    a[j] += (float)v0[j] * w0 + (float)v1[j] * w1;
            }
            for (; i < end; i += 4) {
                int idx = i + par;
                bool act = idx < end;
                const uint2 e0 = edges[act ? idx : end - 1];
                float w0 = act ? (float)__builtin_bit_cast(_Float16, (ushort)(WIDX ? (e0.y >> 16) : (e0.y & 0xFFFFu))) : 0.f;
                const f16x8 v0 = *reinterpret_cast<const f16x8*>(&xh[(long)e0.x * D + dl * 8]);
#pragma unroll
                for (int j = 0; j < 8; ++j)
                    a[j] += (float)v0[j] * w0;
            }
#pragma unroll
            for (int j = 0; j < 8; ++j) {
                a[j] += __shfl_xor(a[j], 16, 64);
                a[j] += __shfl_xor(a[j], 32, 64);
            }
            if (par == 0) {
                f16x8 r;
#pragma unroll
                for (int j = 0; j < 8; ++j) {
                    float v = a[j];
                    v = v > 0.f ? v : 0.01f * v;
                    r[j] = (_Float16)v;
                }
                *reinterpret_cast<f16x8*>(&lds[w][nn][dl * 8]) = r;
            }
        }
    }
    __syncthreads();

    // ---- phase 2: GEMM ----
    int c = l & 15, kg = l >> 4;
    int r0 = base_m + c;  if (r0 >= N_NODES) r0 = N_NODES - 1;

    f32x4 acc[8];
#pragma unroll
    for (int ni = 0; ni < 8; ++ni) acc[ni] = (f32x4)0.f;

    for (int ks = 0; ks < 8; ++ks) {
        int kb = (ks & 3) * 32 + kg * 8;
        f16x8 a0;
        if (ks < 4)
            a0 = *reinterpret_cast<const f16x8*>(&xh[(long)r0 * D + kb]);
        else
            a0 = *reinterpret_cast<const f16x8*>(&lds[w][c][kb]);
        const ushort* wb = &Wt[(size_t)((ks * 4 + kg) * 128) * 8];
#pragma unroll
        for (int ni = 0; ni < 8; ++ni) {
            const f16x8 b = *reinterpret_cast<const f16x8*>(&wb[(ni * 16 + c) * 8]);
            acc[ni] = __builtin_amdgcn_mfma_f32_16x16x32_f16(a0, b, acc[ni], 0, 0, 0);
        }
    }

    float bv[8];
#pragma unroll
    for (int ni = 0; ni < 8; ++ni) bv[ni] = bias[ni * 16 + c];

    if constexpr (!CLS) {
        int rowb = base_m + kg * 4;
#pragma unroll
        for (int r = 0; r < 4; ++r) {
            int row = rowb + r;
            if (row < N_NODES) {
#pragma unroll
                for (int ni = 0; ni < 8; ++ni) {
                    float v = acc[ni][r] + bv[ni];
                    v = v > 0.f ? v : 0.f;
                    outp[(long)row * D + ni * 16 + c] = f2h(v);
                }
            }
        }
    } else {
        // h2 -> LDS (reuse tile), then classifier
        __syncthreads();
#pragma unroll
        for (int r = 0; r < 4; ++r) {
            int lrow = kg * 4 + r;
#pragma unroll
            for (int ni = 0; ni < 8; ++ni) {
                float v = acc[ni][r] + bv[ni];
                v = v > 0.f ? v : 0.f;
                lds[w][lrow][ni * 16 + c] = f2h(v);
            }
        }
        __syncthreads();

        f32x4 bcc[8];
#pragma unroll
        for (int ni = 0; ni < 8; ++ni) bcc[ni] = (f32x4)0.f;

        for (int ks = 0; ks < 4; ++ks) {
            int kb = ks * 32 + kg * 8;
            f16x8 a0 = *reinterpret_cast<const f16x8*>(&lds[w][c][kb]);
            const ushort* wb = &Wl1t[(size_t)((ks * 4 + kg) * 128) * 8];
#pragma unroll
            for (int ni = 0; ni < 8; ++ni) {
                const f16x8 b = *reinterpret_cast<const f16x8*>(&wb[(ni * 16 + c) * 8]);
                bcc[ni] = __builtin_amdgcn_mfma_f32_16x16x32_f16(a0, b, bcc[ni], 0, 0, 0);
            }
        }

        float b1v[8]; float2 w2v[8];
#pragma unroll
        for (int ni = 0; ni < 8; ++ni) {
            b1v[ni] = bl1[ni * 16 + c];
            w2v[ni] = *reinterpret_cast<const float2*>(&Wl2[(ni * 16 + c) * 2]);
        }
        float p0[4] = {0.f, 0.f, 0.f, 0.f};
        float p1[4] = {0.f, 0.f, 0.f, 0.f};
#pragma unroll
        for (int ni = 0; ni < 8; ++ni) {
#pragma unroll
            for (int r = 0; r < 4; ++r) {
                float t = bcc[ni][r] + b1v[ni];
                t = t > 0.f ? t : 0.f;
                p0[r] += t * w2v[ni].x;
                p1[r] += t * w2v[ni].y;
            }
        }
#pragma unroll
        for (int r = 0; r < 4; ++r) {
#pragma unroll
            for (int m = 1; m < 16; m <<= 1) {
                p0[r] += __shfl_xor(p0[r], m, 64);
                p1[r] += __shfl_xor(p1[r], m, 64);
            }
        }
        if (c < 2) {
            int rowb = base_m + kg * 4;
#pragma unroll
            for (int r = 0; r < 4; ++r) {
                int row = rowb + r;
                if (row < N_NODES)
                    outc[(long)row * 2 + c] = (c == 0 ? p0[r] : p1[r]) + bl2[c];
            }
        }
    }
}

// ---------------- launch ----------------

extern "C" void kernel_launch(void* const* d_in, const int* in_sizes, int n_in,
                              void* d_out, int out_size, void* d_ws, size_t ws_size,
                              hipStream_t stream) {
    const float* x   = (const float*)d_in[0];
    const int* esrc  = (const int*)d_in[1];
    const int* edst  = (const int*)d_in[2];
    const float* ew1 = (const float*)d_in[3];
    const float* ew2 = (const float*)d_in[4];
    const float* W1  = (const float*)d_in[5];
    const float* b1  = (const float*)d_in[6];
    const float* W2  = (const float*)d_in[7];
    const float* b2  = (const float*)d_in[8];
    const float* Wl1 = (const float*)d_in[9];
    const float* bl1 = (const float*)d_in[10];
    const float* Wl2 = (const float*)d_in[11];
    const float* bl2 = (const float*)d_in[12];
    float* out = (float*)d_out;

    char* p = (char*)d_ws;
    ushort* h1f     = (ushort*)p;          p += (size_t)N_NODES * D * 2;   // h1 (fp16)
    ushort* xf      = (ushort*)p;          p += (size_t)N_NODES * D * 2;   // x (fp16)
    int* row_ptr    = (int*)p;             p += (size_t)(N_NODES + 16) * 4;
    int* blockhist  = (int*)p;             p += (size_t)SCAN_TOT * 4;      // 307 KB
    int* partials   = (int*)p;             p += 128 * 4;
    uint2* part     = (uint2*)p;           p += (size_t)N_EDGES * 8;       // 12.8 MB
    uint2* packed   = (uint2*)p;           p += (size_t)N_EDGES * 8;       // 12.8 MB
    ushort* W1t     = (ushort*)p;          p += 2 * D * D * 2;
    ushort* W2t     = (ushort*)p;          p += 2 * D * D * 2;
    ushort* Wl1t    = (ushort*)p;          p += D * D * 2;

    // CSR build: two-level partition, LDS atomics only, hierarchical scan
    p1_hist<<<NCHUNK, 256, 0, stream>>>(edst, blockhist);
    scan_a<<<SC_NB, 256, 0, stream>>>(blockhist, partials);
    scan_b<<<1, 128, 0, stream>>>(partials, row_ptr);
    scan_c<<<SC_NB, 256, 0, stream>>>(blockhist, partials);
    p1_scatter<<<NCHUNK, 256, 0, stream>>>(esrc, edst, ew1, ew2, blockhist, part);
    p2_kernel<<<NBIN, 256, 0, stream>>>(blockhist, part, row_ptr, packed);

    cvt_f16_kernel<<<(N_NODES * D) / (256 * 8), 256, 0, stream>>>(x, xf);
    wtile_all_kernel<<<(5 * D * D + 255) / 256, 256, 0, stream>>>(W1, W2, Wl1,
                                                                  W1t, W2t, Wl1t);

    int ggrid = (N_NODES + 63) / 64;   // 1563

    // layer 1: fused spmm + gemm
    spmm_gemm_kernel<0, false><<<ggrid, 256, 0, stream>>>(
        xf, packed, row_ptr, W1t, b1, h1f, nullptr, nullptr, nullptr, nullptr, nullptr);
    // layer 2: fused spmm + gemm + classifier (agg & h2 never touch global)
    spmm_gemm_kernel<1, true><<<ggrid, 256, 0, stream>>>(
        h1f, packed, row_ptr, W2t, b2, nullptr, Wl1t, bl1, Wl2, bl2, out);
}

// Round 15
// 243.281 us; speedup vs baseline: 1.1594x; 1.1594x over previous
//
#include <hip/hip_runtime.h>
#include <hip/hip_fp16.h>

#define N_NODES 100000
#define N_EDGES 1600000
#define D 128

#define NBIN 196            // coarse bins: dst>>9, 512 nodes each
#define NCHUNK 391          // edge chunks of 4096
#define CHUNK_E 4096
#define SCAN_TOT (NBIN * NCHUNK)   // 76636
#define SC_NB ((SCAN_TOT + 1023) / 1024)   // 75

#define WT_BLK 320          // wtile blocks: 5*D*D/256
#define CVT_BLK 6250        // cvt blocks: N_NODES*D/(256*8)

typedef __attribute__((ext_vector_type(8))) _Float16 f16x8;
typedef __attribute__((ext_vector_type(4))) float f32x4;

__device__ __forceinline__ float h2f(ushort u) {
    __half_raw r; r.x = u;
    return __half2float(__half(r));
}
__device__ __forceinline__ ushort f2h(float f) {
    __half_raw r = __half_raw(__float2half(f));
    return r.x;
}

// ---------------- prep: p1_hist + wtile + cvt merged (independent, one launch) ----

__global__ __launch_bounds__(256) void prep_kernel(const int* __restrict__ dst,
                                                   int* __restrict__ blockhist,
                                                   const float* __restrict__ W1,
                                                   const float* __restrict__ W2,
                                                   const float* __restrict__ Wl1,
                                                   ushort* __restrict__ W1t,
                                                   ushort* __restrict__ W2t,
                                                   ushort* __restrict__ Wl1t,
                                                   const float* __restrict__ x,
                                                   ushort* __restrict__ xf) {
    __shared__ int h[NBIN];
    int tid = threadIdx.x;
    int b = blockIdx.x;
    if (b < NCHUNK) {
        // ---- histogram over coarse bins ----
        for (int i = tid; i < NBIN; i += 256) h[i] = 0;
        __syncthreads();
        int base = b * CHUNK_E;
#pragma unroll
        for (int j = 0; j < 16; ++j) {
            int i = base + j * 256 + tid;
            if (i < N_EDGES) atomicAdd(&h[dst[i] >> 9], 1);
        }
        __syncthreads();
        for (int i = tid; i < NBIN; i += 256)
            blockhist[i * NCHUNK + b] = h[i];
    } else if (b < NCHUNK + WT_BLK) {
        // ---- W tiling: fragment-ordered fp16 ----
        int i = (b - NCHUNK) * 256 + tid;
        const int DD2 = 2 * D * D;
        const float* src; ushort* dstp; int j;
        if (i < DD2)                  { src = W1;  dstp = W1t;  j = i; }
        else if (i < 2 * DD2)         { src = W2;  dstp = W2t;  j = i - DD2; }
        else                          { src = Wl1; dstp = Wl1t; j = i - 2 * DD2; }
        int k = j >> 7, n = j & 127;
        int addr = (((k >> 3) << 7) + n) * 8 + (k & 7);
        dstp[addr] = f2h(src[j]);
    } else {
        // ---- fp32 -> fp16 convert, 8 elems/thread ----
        long i = ((long)(b - NCHUNK - WT_BLK) * 256 + tid) * 8;
        const float4 a = *reinterpret_cast<const float4*>(&x[i]);
        const float4 c = *reinterpret_cast<const float4*>(&x[i + 4]);
        ushort4 u0, u1;
        u0.x = f2h(a.x); u0.y = f2h(a.y); u0.z = f2h(a.z); u0.w = f2h(a.w);
        u1.x = f2h(c.x); u1.y = f2h(c.y); u1.z = f2h(c.z); u1.w = f2h(c.w);
        *reinterpret_cast<ushort4*>(&xf[i]) = u0;
        *reinterpret_cast<ushort4*>(&xf[i + 4]) = u1;
    }
}

// ---- hierarchical exclusive scan of blockhist[SCAN_TOT] (in place, 2 kernels) ----

__global__ __launch_bounds__(256) void scan_a(const int* __restrict__ bh,
                                              int* __restrict__ partials) {
    __shared__ int sums[256];
    int tid = threadIdx.x;
    int base = blockIdx.x * 1024 + tid * 4;
    int s = 0;
#pragma unroll
    for (int i = 0; i < 4; ++i) {
        int idx = base + i;
        if (idx < SCAN_TOT) s += bh[idx];
    }
    sums[tid] = s;
    __syncthreads();
#pragma unroll
    for (int off = 128; off > 0; off >>= 1) {
        if (tid < off) sums[tid] += sums[tid + off];
        __syncthreads();
    }
    if (tid == 0) partials[blockIdx.x] = sums[0];
}

// scan_c computes its own block offset from raw partials (scan_b eliminated)
__global__ __launch_bounds__(256) void scan_c(int* __restrict__ bh,
                                              const int* __restrict__ partials,
                                              int* __restrict__ row_ptr) {
    __shared__ int tsum[256];
    __shared__ int red[128];
    __shared__ int offs;
    int tid = threadIdx.x;

    // block offset = sum of partials[j], j < blockIdx.x
    if (tid < 128) {
        int v = (tid < blockIdx.x) ? partials[tid] : 0;   // blockIdx.x <= 74 < 128
        red[tid] = v;
    }
    __syncthreads();
#pragma unroll
    for (int off = 64; off > 0; off >>= 1) {
        if (tid < off) red[tid] += red[tid + off];
        __syncthreads();
    }
    if (tid == 0) {
        offs = red[0];
        if (blockIdx.x == 0) row_ptr[N_NODES] = N_EDGES;
    }
    __syncthreads();

    int base = blockIdx.x * 1024 + tid * 4;
    int d[4];
#pragma unroll
    for (int i = 0; i < 4; ++i)
        d[i] = (base + i < SCAN_TOT) ? bh[base + i] : 0;
    int s = d[0] + d[1] + d[2] + d[3];
    tsum[tid] = s;
    __syncthreads();
    for (int off = 1; off < 256; off <<= 1) {
        int t = (tid >= off) ? tsum[tid - off] : 0;
        __syncthreads();
        tsum[tid] += t;
        __syncthreads();
    }
    int run = offs + tsum[tid] - s;   // exclusive start
#pragma unroll
    for (int i = 0; i < 4; ++i) {
        int idx = base + i;
        if (idx < SCAN_TOT) {
            bh[idx] = run;
            run += d[i];
        }
    }
}

// record: {src | dstLocal<<17, w1h | w2h<<16}
__global__ __launch_bounds__(256) void p1_scatter(const int* __restrict__ src,
                                                  const int* __restrict__ dst,
                                                  const float* __restrict__ w1,
                                                  const float* __restrict__ w2,
                                                  const int* __restrict__ bh,
                                                  uint2* __restrict__ part) {
    __shared__ int cur[NBIN];
    int tid = threadIdx.x;
    for (int b = tid; b < NBIN; b += 256) cur[b] = bh[b * NCHUNK + blockIdx.x];
    __syncthreads();
    int base = blockIdx.x * CHUNK_E;
#pragma unroll
    for (int j = 0; j < 16; ++j) {
        int i = base + j * 256 + tid;
        if (i < N_EDGES) {
            int d = dst[i];
            int pos = atomicAdd(&cur[d >> 9], 1);
            uint2 e;
            e.x = (unsigned)src[i] | ((unsigned)(d & 511) << 17);
            e.y = (unsigned)f2h(w1[i]) | ((unsigned)f2h(w2[i]) << 16);
            part[pos] = e;
        }
    }
}

// ---------------- P2: per-bin fine grouping -> exact CSR, deg_inv folded ----------

__global__ __launch_bounds__(256) void p2_kernel(const int* __restrict__ bh,
                                                 const uint2* __restrict__ part,
                                                 int* __restrict__ row_ptr,
                                                 uint2* __restrict__ packed) {
    __shared__ int deg2[512];
    __shared__ int cur[512];
    __shared__ int sb[256];
    int tid = threadIdx.x;
    int bin = blockIdx.x;
    int base = bh[bin * NCHUNK];
    int endv = (bin == NBIN - 1) ? N_EDGES : bh[(bin + 1) * NCHUNK];
    int cnt = endv - base;
    deg2[tid] = 0; deg2[tid + 256] = 0;
    __syncthreads();
    for (int k = tid; k < cnt; k += 256)
        atomicAdd(&deg2[part[base + k].x >> 17], 1);
    __syncthreads();
    int s0 = deg2[2 * tid], s1 = deg2[2 * tid + 1];
    int ts = s0 + s1;
    sb[tid] = ts;
    __syncthreads();
    for (int off = 1; off < 256; off <<= 1) {
        int v = (tid >= off) ? sb[tid - off] : 0;
        __syncthreads();
        sb[tid] += v;
        __syncthreads();
    }
    int ex = sb[tid] - ts;                     // exclusive within bin
    cur[2 * tid] = ex;
    cur[2 * tid + 1] = ex + s0;
    int node0 = bin * 512 + 2 * tid;
    if (node0 < N_NODES)     row_ptr[node0]     = base + ex;
    if (node0 + 1 < N_NODES) row_ptr[node0 + 1] = base + ex + s0;
    __syncthreads();
    for (int k = tid; k < cnt; k += 256) {
        uint2 r = part[base + k];
        int local = r.x >> 17;
        float di = 1.0f / (float)deg2[local];
        int pos = base + atomicAdd(&cur[local], 1);
        uint2 e;
        e.x = r.x & 0x1FFFFu;
        e.y = (unsigned)f2h(h2f((ushort)(r.y & 0xFFFFu)) * di)
            | ((unsigned)f2h(h2f((ushort)(r.y >> 16)) * di) << 16);
        packed[pos] = e;
    }
}

// ---------------- SpMM: CSR gather of fp16 rows + leaky-relu ----------------
// wave-per-node; 16 lanes cover a row (f16x8/lane); lane>>4 = edge parity (4-way).

template<int WIDX>
__global__ __launch_bounds__(256) void spmm_kernel(const ushort* __restrict__ xin,
                                                   const uint2* __restrict__ edges,
                                                   const int* __restrict__ row_ptr,
                                                   ushort* __restrict__ out) {
    int wid = threadIdx.x >> 6;
    int lane = threadIdx.x & 63;
    int par = lane >> 4;                   // edge parity 0..3
    int dl = lane & 15;                    // dim group: dims 8*dl..8*dl+7
    int n = blockIdx.x * 4 + wid;
    int beg = row_ptr[n], end = row_ptr[n + 1];
    float a[8] = {0.f, 0.f, 0.f, 0.f, 0.f, 0.f, 0.f, 0.f};

    const _Float16* xh = reinterpret_cast<const _Float16*>(xin);

    int i = beg;
    for (; i + 15 < end; i += 16) {
        const uint2 e0 = edges[i + par];
        const uint2 e1 = edges[i + 4 + par];
        const uint2 e2 = edges[i + 8 + par];
        const uint2 e3 = edges[i + 12 + par];
        float w0 = (float)__builtin_bit_cast(_Float16, (ushort)(WIDX ? (e0.y >> 16) : (e0.y & 0xFFFFu)));
        float w1 = (float)__builtin_bit_cast(_Float16, (ushort)(WIDX ? (e1.y >> 16) : (e1.y & 0xFFFFu)));
        float w2 = (float)__builtin_bit_cast(_Float16, (ushort)(WIDX ? (e2.y >> 16) : (e2.y & 0xFFFFu)));
        float w3 = (float)__builtin_bit_cast(_Float16, (ushort)(WIDX ? (e3.y >> 16) : (e3.y & 0xFFFFu)));
        const f16x8 v0 = *reinterpret_cast<const f16x8*>(&xh[(long)e0.x * D + dl * 8]);
        const f16x8 v1 = *reinterpret_cast<const f16x8*>(&xh[(long)e1.x * D + dl * 8]);
        const f16x8 v2 = *reinterpret_cast<const f16x8*>(&xh[(long)e2.x * D + dl * 8]);
        const f16x8 v3 = *reinterpret_cast<const f16x8*>(&xh[(long)e3.x * D + dl * 8]);
#pragma unroll
        for (int j = 0; j < 8; ++j)
            a[j] += (float)v0[j] * w0 + (float)v1[j] * w1
                  + (float)v2[j] * w2 + (float)v3[j] * w3;
    }
    for (; i + 7 < end; i += 8) {
        const uint2 e0 = edges[i + par];
        const uint2 e1 = edges[i + 4 + par];
        float w0 = (float)__builtin_bit_cast(_Float16, (ushort)(WIDX ? (e0.y >> 16) : (e0.y & 0xFFFFu)));
        float w1 = (float)__builtin_bit_cast(_Float16, (ushort)(WIDX ? (e1.y >> 16) : (e1.y & 0xFFFFu)));
        const f16x8 v0 = *reinterpret_cast<const f16x8*>(&xh[(long)e0.x * D + dl * 8]);
        const f16x8 v1 = *reinterpret_cast<const f16x8*>(&xh[(long)e1.x * D + dl * 8]);
#pragma unroll
        for (int j = 0; j < 8; ++j)
            a[j] += (float)v0[j] * w0 + (float)v1[j] * w1;
    }
    for (; i < end; i += 4) {
        int idx = i + par;
        bool act = idx < end;
        const uint2 e0 = edges[act ? idx : end - 1];
        float w0 = act ? (float)__builtin_bit_cast(_Float16, (ushort)(WIDX ? (e0.y >> 16) : (e0.y & 0xFFFFu))) : 0.f;
        const f16x8 v0 = *reinterpret_cast<const f16x8*>(&xh[(long)e0.x * D + dl * 8]);
#pragma unroll
        for (int j = 0; j < 8; ++j)
            a[j] += (float)v0[j] * w0;
    }

#pragma unroll
    for (int j = 0; j < 8; ++j) {
        a[j] += __shfl_xor(a[j], 16, 64);
        a[j] += __shfl_xor(a[j], 32, 64);
    }

    if (par == 0) {
        ushort4 r0, r1;
        float v;
        v = a[0]; v = v > 0.f ? v : 0.01f * v; r0.x = f2h(v);
        v = a[1]; v = v > 0.f ? v : 0.01f * v; r0.y = f2h(v);
        v = a[2]; v = v > 0.f ? v : 0.01f * v; r0.z = f2h(v);
        v = a[3]; v = v > 0.f ? v : 0.01f * v; r0.w = f2h(v);
        v = a[4]; v = v > 0.f ? v : 0.01f * v; r1.x = f2h(v);
        v = a[5]; v = v > 0.f ? v : 0.01f * v; r1.y = f2h(v);
        v = a[6]; v = v > 0.f ? v : 0.01f * v; r1.z = f2h(v);
        v = a[7]; v = v > 0.f ? v : 0.01f * v; r1.w = f2h(v);
        *reinterpret_cast<ushort4*>(&out[(long)n * D + dl * 8]) = r0;
        *reinterpret_cast<ushort4*>(&out[(long)n * D + dl * 8 + 4]) = r1;
    }
}

// ---------------- MFMA fp16 GEMM: 16 rows per wave (occupancy-oriented) ----------
// out = relu([in1|in2] @ W + b) as fp16. Grid: ceil(N/64) blocks x 4 waves.

__global__ __launch_bounds__(256) void gemm_mfma_kernel(
        const ushort* __restrict__ in1,
        const ushort* __restrict__ in2,
        const ushort* __restrict__ Wt,
        const float* __restrict__ bias,
        ushort* __restrict__ outp) {
    int tid = threadIdx.x;
    int w = tid >> 6, l = tid & 63;
    int c = l & 15, kg = l >> 4;
    int base_m = blockIdx.x * 64 + w * 16;
    int r0 = base_m + c;  if (r0 >= N_NODES) r0 = N_NODES - 1;

    f32x4 acc[8];
#pragma unroll
    for (int ni = 0; ni < 8; ++ni) acc[ni] = (f32x4)0.f;

    for (int ks = 0; ks < 8; ++ks) {
        int kb = (ks & 3) * 32 + kg * 8;
        const ushort* src = (ks < 4) ? in1 : in2;
        f16x8 a0 = *reinterpret_cast<const f16x8*>(&src[(long)r0 * D + kb]);
        const ushort* wb = &Wt[(size_t)((ks * 4 + kg) * 128) * 8];
#pragma unroll
        for (int ni = 0; ni < 8; ++ni) {
            const f16x8 b = *reinterpret_cast<const f16x8*>(&wb[(ni * 16 + c) * 8]);
            acc[ni] = __builtin_amdgcn_mfma_f32_16x16x32_f16(a0, b, acc[ni], 0, 0, 0);
        }
    }

    float bv[8];
#pragma unroll
    for (int ni = 0; ni < 8; ++ni) bv[ni] = bias[ni * 16 + c];
    int rowb = base_m + kg * 4;
#pragma unroll
    for (int r = 0; r < 4; ++r) {
        int row = rowb + r;
        if (row < N_NODES) {
#pragma unroll
            for (int ni = 0; ni < 8; ++ni) {
                float v = acc[ni][r] + bv[ni];
                v = v > 0.f ? v : 0.f;
                outp[(long)row * D + ni * 16 + c] = f2h(v);
            }
        }
    }
}

// ---------------- Fused layer-2 GEMM + classifier (16 rows per wave) ----------

#define LSTR 136   // LDS row stride in shorts

__global__ __launch_bounds__(256) void gemm2_cls_kernel(
        const ushort* __restrict__ in1,
        const ushort* __restrict__ in2,
        const ushort* __restrict__ W2t,
        const float* __restrict__ b2,
        const ushort* __restrict__ Wl1t,
        const float* __restrict__ bl1,
        const float* __restrict__ Wl2,
        const float* __restrict__ bl2,
        float* __restrict__ out) {
    __shared__ __align__(16) ushort lds_h2[4][16][LSTR];
    int tid = threadIdx.x;
    int w = tid >> 6, l = tid & 63;
    int c = l & 15, kg = l >> 4;
    int base_m = blockIdx.x * 64 + w * 16;
    int r0 = base_m + c;  if (r0 >= N_NODES) r0 = N_NODES - 1;

    // ---- phase A: h2 fragments ----
    f32x4 acc[8];
#pragma unroll
    for (int ni = 0; ni < 8; ++ni) acc[ni] = (f32x4)0.f;

    for (int ks = 0; ks < 8; ++ks) {
        int kb = (ks & 3) * 32 + kg * 8;
        const ushort* src = (ks < 4) ? in1 : in2;
        f16x8 a0 = *reinterpret_cast<const f16x8*>(&src[(long)r0 * D + kb]);
        const ushort* wb = &W2t[(size_t)((ks * 4 + kg) * 128) * 8];
#pragma unroll
        for (int ni = 0; ni < 8; ++ni) {
            const f16x8 b = *reinterpret_cast<const f16x8*>(&wb[(ni * 16 + c) * 8]);
            acc[ni] = __builtin_amdgcn_mfma_f32_16x16x32_f16(a0, b, acc[ni], 0, 0, 0);
        }
    }

    float bv[8];
#pragma unroll
    for (int ni = 0; ni < 8; ++ni) bv[ni] = b2[ni * 16 + c];
#pragma unroll
    for (int r = 0; r < 4; ++r) {
        int lrow = kg * 4 + r;
#pragma unroll
        for (int ni = 0; ni < 8; ++ni) {
            float v = acc[ni][r] + bv[ni];
            v = v > 0.f ? v : 0.f;
            lds_h2[w][lrow][ni * 16 + c] = f2h(v);
        }
    }
    __syncthreads();

    // ---- phase B: classifier on the wave's 16 h2 rows ----
    f32x4 bcc[8];
#pragma unroll
    for (int ni = 0; ni < 8; ++ni) bcc[ni] = (f32x4)0.f;

    for (int ks = 0; ks < 4; ++ks) {
        int kb = ks * 32 + kg * 8;
        f16x8 a0 = *reinterpret_cast<const f16x8*>(&lds_h2[w][c][kb]);
        const ushort* wb = &Wl1t[(size_t)((ks * 4 + kg) * 128) * 8];
#pragma unroll
        for (int ni = 0; ni < 8; ++ni) {
            const f16x8 b = *reinterpret_cast<const f16x8*>(&wb[(ni * 16 + c) * 8]);
            bcc[ni] = __builtin_amdgcn_mfma_f32_16x16x32_f16(a0, b, bcc[ni], 0, 0, 0);
        }
    }

    float b1v[8]; float2 w2v[8];
#pragma unroll
    for (int ni = 0; ni < 8; ++ni) {
        b1v[ni] = bl1[ni * 16 + c];
        w2v[ni] = *reinterpret_cast<const float2*>(&Wl2[(ni * 16 + c) * 2]);
    }
    float p0[4] = {0.f, 0.f, 0.f, 0.f};
    float p1[4] = {0.f, 0.f, 0.f, 0.f};
#pragma unroll
    for (int ni = 0; ni < 8; ++ni) {
#pragma unroll
        for (int r = 0; r < 4; ++r) {
            float t = bcc[ni][r] + b1v[ni];
            t = t > 0.f ? t : 0.f;
            p0[r] += t * w2v[ni].x;
            p1[r] += t * w2v[ni].y;
        }
    }
#pragma unroll
    for (int r = 0; r < 4; ++r) {
#pragma unroll
        for (int m = 1; m < 16; m <<= 1) {
            p0[r] += __shfl_xor(p0[r], m, 64);
            p1[r] += __shfl_xor(p1[r], m, 64);
        }
    }
    if (c < 2) {
        int rowb = base_m + kg * 4;
#pragma unroll
        for (int r = 0; r < 4; ++r) {
            int row = rowb + r;
            if (row < N_NODES)
                out[(long)row * 2 + c] = (c == 0 ? p0[r] : p1[r]) + bl2[c];
        }
    }
}

// ---------------- launch ----------------

extern "C" void kernel_launch(void* const* d_in, const int* in_sizes, int n_in,
                              void* d_out, int out_size, void* d_ws, size_t ws_size,
                              hipStream_t stream) {
    const float* x   = (const float*)d_in[0];
    const int* esrc  = (const int*)d_in[1];
    const int* edst  = (const int*)d_in[2];
    const float* ew1 = (const float*)d_in[3];
    const float* ew2 = (const float*)d_in[4];
    const float* W1  = (const float*)d_in[5];
    const float* b1  = (const float*)d_in[6];
    const float* W2  = (const float*)d_in[7];
    const float* b2  = (const float*)d_in[8];
    const float* Wl1 = (const float*)d_in[9];
    const float* bl1 = (const float*)d_in[10];
    const float* Wl2 = (const float*)d_in[11];
    const float* bl2 = (const float*)d_in[12];
    float* out = (float*)d_out;

    char* p = (char*)d_ws;
    ushort* Af      = (ushort*)p;          p += (size_t)N_NODES * D * 2;   // agg (fp16)
    ushort* h1f     = (ushort*)p;          p += (size_t)N_NODES * D * 2;   // h1 (fp16)
    ushort* xf      = (ushort*)p;          p += (size_t)N_NODES * D * 2;   // x (fp16)
    int* row_ptr    = (int*)p;             p += (size_t)(N_NODES + 16) * 4;
    int* blockhist  = (int*)p;             p += (size_t)SCAN_TOT * 4;      // 307 KB
    int* partials   = (int*)p;             p += 128 * 4;
    uint2* part     = (uint2*)p;           p += (size_t)N_EDGES * 8;       // 12.8 MB
    uint2* packed   = (uint2*)p;           p += (size_t)N_EDGES * 8;       // 12.8 MB
    ushort* W1t     = (ushort*)p;          p += 2 * D * D * 2;
    ushort* W2t     = (ushort*)p;          p += 2 * D * D * 2;
    ushort* Wl1t    = (ushort*)p;          p += D * D * 2;

    // prep: histogram + W tiling + x convert in one launch (independent work)
    prep_kernel<<<NCHUNK + WT_BLK + CVT_BLK, 256, 0, stream>>>(
        edst, blockhist, W1, W2, Wl1, W1t, W2t, Wl1t, x, xf);
    // scan (2 kernels: block sums, then offset-aware local scan)
    scan_a<<<SC_NB, 256, 0, stream>>>(blockhist, partials);
    scan_c<<<SC_NB, 256, 0, stream>>>(blockhist, partials, row_ptr);
    p1_scatter<<<NCHUNK, 256, 0, stream>>>(esrc, edst, ew1, ew2, blockhist, part);
    p2_kernel<<<NBIN, 256, 0, stream>>>(blockhist, part, row_ptr, packed);

    int ggrid = (N_NODES + 63) / 64;   // 1563

    // layer 1
    spmm_kernel<0><<<N_NODES / 4, 256, 0, stream>>>(xf, packed, row_ptr, Af);
    gemm_mfma_kernel<<<ggrid, 256, 0, stream>>>(xf, Af, W1t, b1, h1f);
    // layer 2 + classifier fused (h2 never touches global memory)
    spmm_kernel<1><<<N_NODES / 4, 256, 0, stream>>>(h1f, packed, row_ptr, Af);
    gemm2_cls_kernel<<<ggrid, 256, 0, stream>>>(h1f, Af, W2t, b2, Wl1t, bl1, Wl2, bl2, out);
}

// Round 16
// 222.697 us; speedup vs baseline: 1.2665x; 1.0924x over previous
//
#include <hip/hip_runtime.h>
#include <hip/hip_fp16.h>

#define N_NODES 100000
#define N_EDGES 1600000
#define D 128

#define NBIN 196            // coarse bins: dst>>9, 512 nodes each
#define NCHUNK 391          // edge chunks of 4096
#define CHUNK_E 4096
#define SCAN_TOT (NBIN * NCHUNK)   // 76636
#define SC_NB ((SCAN_TOT + 1023) / 1024)   // 75

#define WT_BLK 320          // wtile blocks: 5*D*D/256
#define CVT_BLK 6250        // cvt blocks: N_NODES*D/(256*8)

typedef __attribute__((ext_vector_type(8))) _Float16 f16x8;
typedef __attribute__((ext_vector_type(4))) float f32x4;

__device__ __forceinline__ float h2f(ushort u) {
    __half_raw r; r.x = u;
    return __half2float(__half(r));
}
__device__ __forceinline__ ushort f2h(float f) {
    __half_raw r = __half_raw(__float2half(f));
    return r.x;
}

// ---------------- prep: p1_hist + wtile + cvt merged (independent, one launch) ----

__global__ __launch_bounds__(256) void prep_kernel(const int* __restrict__ dst,
                                                   int* __restrict__ blockhist,
                                                   const float* __restrict__ W1,
                                                   const float* __restrict__ W2,
                                                   const float* __restrict__ Wl1,
                                                   ushort* __restrict__ W1t,
                                                   ushort* __restrict__ W2t,
                                                   ushort* __restrict__ Wl1t,
                                                   const float* __restrict__ x,
                                                   ushort* __restrict__ xf) {
    __shared__ int h[NBIN];
    int tid = threadIdx.x;
    int b = blockIdx.x;
    if (b < NCHUNK) {
        for (int i = tid; i < NBIN; i += 256) h[i] = 0;
        __syncthreads();
        int base = b * CHUNK_E;
#pragma unroll
        for (int j = 0; j < 16; ++j) {
            int i = base + j * 256 + tid;
            if (i < N_EDGES) atomicAdd(&h[dst[i] >> 9], 1);
        }
        __syncthreads();
        for (int i = tid; i < NBIN; i += 256)
            blockhist[i * NCHUNK + b] = h[i];
    } else if (b < NCHUNK + WT_BLK) {
        int i = (b - NCHUNK) * 256 + tid;
        const int DD2 = 2 * D * D;
        const float* src; ushort* dstp; int j;
        if (i < DD2)                  { src = W1;  dstp = W1t;  j = i; }
        else if (i < 2 * DD2)         { src = W2;  dstp = W2t;  j = i - DD2; }
        else                          { src = Wl1; dstp = Wl1t; j = i - 2 * DD2; }
        int k = j >> 7, n = j & 127;
        int addr = (((k >> 3) << 7) + n) * 8 + (k & 7);
        dstp[addr] = f2h(src[j]);
    } else {
        long i = ((long)(b - NCHUNK - WT_BLK) * 256 + tid) * 8;
        const float4 a = *reinterpret_cast<const float4*>(&x[i]);
        const float4 c = *reinterpret_cast<const float4*>(&x[i + 4]);
        ushort4 u0, u1;
        u0.x = f2h(a.x); u0.y = f2h(a.y); u0.z = f2h(a.z); u0.w = f2h(a.w);
        u1.x = f2h(c.x); u1.y = f2h(c.y); u1.z = f2h(c.z); u1.w = f2h(c.w);
        *reinterpret_cast<ushort4*>(&xf[i]) = u0;
        *reinterpret_cast<ushort4*>(&xf[i + 4]) = u1;
    }
}

// ---- hierarchical exclusive scan of blockhist[SCAN_TOT] (in place, 2 kernels) ----

__global__ __launch_bounds__(256) void scan_a(const int* __restrict__ bh,
                                              int* __restrict__ partials) {
    __shared__ int sums[256];
    int tid = threadIdx.x;
    int base = blockIdx.x * 1024 + tid * 4;
    int s = 0;
#pragma unroll
    for (int i = 0; i < 4; ++i) {
        int idx = base + i;
        if (idx < SCAN_TOT) s += bh[idx];
    }
    sums[tid] = s;
    __syncthreads();
#pragma unroll
    for (int off = 128; off > 0; off >>= 1) {
        if (tid < off) sums[tid] += sums[tid + off];
        __syncthreads();
    }
    if (tid == 0) partials[blockIdx.x] = sums[0];
}

__global__ __launch_bounds__(256) void scan_c(int* __restrict__ bh,
                                              const int* __restrict__ partials,
                                              int* __restrict__ row_ptr) {
    __shared__ int tsum[256];
    __shared__ int red[128];
    __shared__ int offs;
    int tid = threadIdx.x;

    if (tid < 128) {
        int v = (tid < blockIdx.x) ? partials[tid] : 0;
        red[tid] = v;
    }
    __syncthreads();
#pragma unroll
    for (int off = 64; off > 0; off >>= 1) {
        if (tid < off) red[tid] += red[tid + off];
        __syncthreads();
    }
    if (tid == 0) {
        offs = red[0];
        if (blockIdx.x == 0) row_ptr[N_NODES] = N_EDGES;
    }
    __syncthreads();

    int base = blockIdx.x * 1024 + tid * 4;
    int d[4];
#pragma unroll
    for (int i = 0; i < 4; ++i)
        d[i] = (base + i < SCAN_TOT) ? bh[base + i] : 0;
    int s = d[0] + d[1] + d[2] + d[3];
    tsum[tid] = s;
    __syncthreads();
    for (int off = 1; off < 256; off <<= 1) {
        int t = (tid >= off) ? tsum[tid - off] : 0;
        __syncthreads();
        tsum[tid] += t;
        __syncthreads();
    }
    int run = offs + tsum[tid] - s;
#pragma unroll
    for (int i = 0; i < 4; ++i) {
        int idx = base + i;
        if (idx < SCAN_TOT) {
            bh[idx] = run;
            run += d[i];
        }
    }
}

// record: {src | dstLocal<<17, w1h | w2h<<16}; 4 edges/thread vectorized
__global__ __launch_bounds__(256) void p1_scatter(const int* __restrict__ src,
                                                  const int* __restrict__ dst,
                                                  const float* __restrict__ w1,
                                                  const float* __restrict__ w2,
                                                  const int* __restrict__ bh,
                                                  uint2* __restrict__ part) {
    __shared__ int cur[NBIN];
    int tid = threadIdx.x;
    for (int b = tid; b < NBIN; b += 256) cur[b] = bh[b * NCHUNK + blockIdx.x];
    __syncthreads();
    int base = blockIdx.x * CHUNK_E;
#pragma unroll
    for (int j = 0; j < 4; ++j) {
        int i0 = base + (j * 256 + tid) * 4;
        if (i0 + 3 < N_EDGES) {
            const int4 d4 = *reinterpret_cast<const int4*>(&dst[i0]);
            const int4 s4 = *reinterpret_cast<const int4*>(&src[i0]);
            const float4 a4 = *reinterpret_cast<const float4*>(&w1[i0]);
            const float4 b4 = *reinterpret_cast<const float4*>(&w2[i0]);
            uint2 e;
            int pos;
            pos = atomicAdd(&cur[d4.x >> 9], 1);
            e.x = (unsigned)s4.x | ((unsigned)(d4.x & 511) << 17);
            e.y = (unsigned)f2h(a4.x) | ((unsigned)f2h(b4.x) << 16);
            part[pos] = e;
            pos = atomicAdd(&cur[d4.y >> 9], 1);
            e.x = (unsigned)s4.y | ((unsigned)(d4.y & 511) << 17);
            e.y = (unsigned)f2h(a4.y) | ((unsigned)f2h(b4.y) << 16);
            part[pos] = e;
            pos = atomicAdd(&cur[d4.z >> 9], 1);
            e.x = (unsigned)s4.z | ((unsigned)(d4.z & 511) << 17);
            e.y = (unsigned)f2h(a4.z) | ((unsigned)f2h(b4.z) << 16);
            part[pos] = e;
            pos = atomicAdd(&cur[d4.w >> 9], 1);
            e.x = (unsigned)s4.w | ((unsigned)(d4.w & 511) << 17);
            e.y = (unsigned)f2h(a4.w) | ((unsigned)f2h(b4.w) << 16);
            part[pos] = e;
        } else {
            for (int i = i0; i < N_EDGES; ++i) {
                int d = dst[i];
                int pos = atomicAdd(&cur[d >> 9], 1);
                uint2 e;
                e.x = (unsigned)src[i] | ((unsigned)(d & 511) << 17);
                e.y = (unsigned)f2h(w1[i]) | ((unsigned)f2h(w2[i]) << 16);
                part[pos] = e;
            }
        }
    }
}

// ---------------- P2: per-bin fine grouping -> exact CSR, deg_inv folded ----------

__global__ __launch_bounds__(256) void p2_kernel(const int* __restrict__ bh,
                                                 const uint2* __restrict__ part,
                                                 int* __restrict__ row_ptr,
                                                 uint2* __restrict__ packed) {
    __shared__ int deg2[512];
    __shared__ int cur[512];
    __shared__ int sb[256];
    int tid = threadIdx.x;
    int bin = blockIdx.x;
    int base = bh[bin * NCHUNK];
    int endv = (bin == NBIN - 1) ? N_EDGES : bh[(bin + 1) * NCHUNK];
    int cnt = endv - base;
    deg2[tid] = 0; deg2[tid + 256] = 0;
    __syncthreads();
    for (int k = tid; k < cnt; k += 256)
        atomicAdd(&deg2[part[base + k].x >> 17], 1);
    __syncthreads();
    int s0 = deg2[2 * tid], s1 = deg2[2 * tid + 1];
    int ts = s0 + s1;
    sb[tid] = ts;
    __syncthreads();
    for (int off = 1; off < 256; off <<= 1) {
        int v = (tid >= off) ? sb[tid - off] : 0;
        __syncthreads();
        sb[tid] += v;
        __syncthreads();
    }
    int ex = sb[tid] - ts;
    cur[2 * tid] = ex;
    cur[2 * tid + 1] = ex + s0;
    int node0 = bin * 512 + 2 * tid;
    if (node0 < N_NODES)     row_ptr[node0]     = base + ex;
    if (node0 + 1 < N_NODES) row_ptr[node0 + 1] = base + ex + s0;
    __syncthreads();
    for (int k = tid; k < cnt; k += 256) {
        uint2 r = part[base + k];
        int local = r.x >> 17;
        float di = 1.0f / (float)deg2[local];
        int pos = base + atomicAdd(&cur[local], 1);
        uint2 e;
        e.x = r.x & 0x1FFFFu;
        e.y = (unsigned)f2h(h2f((ushort)(r.y & 0xFFFFu)) * di)
            | ((unsigned)f2h(h2f((ushort)(r.y >> 16)) * di) << 16);
        packed[pos] = e;
    }
}

// ---------------- SpMM: CSR gather of fp16 rows + leaky-relu ----------------
// wave-per-node; 16 lanes cover a row (f16x8/lane); lane>>4 = edge parity (4-way).

template<int WIDX>
__global__ __launch_bounds__(256) void spmm_kernel(const ushort* __restrict__ xin,
                                                   const uint2* __restrict__ edges,
                                                   const int* __restrict__ row_ptr,
                                                   ushort* __restrict__ out) {
    int wid = threadIdx.x >> 6;
    int lane = threadIdx.x & 63;
    int par = lane >> 4;
    int dl = lane & 15;
    int n = blockIdx.x * 4 + wid;
    int beg = row_ptr[n], end = row_ptr[n + 1];
    float a[8] = {0.f, 0.f, 0.f, 0.f, 0.f, 0.f, 0.f, 0.f};

    const _Float16* xh = reinterpret_cast<const _Float16*>(xin);

    int i = beg;
    for (; i + 15 < end; i += 16) {
        const uint2 e0 = edges[i + par];
        const uint2 e1 = edges[i + 4 + par];
        const uint2 e2 = edges[i + 8 + par];
        const uint2 e3 = edges[i + 12 + par];
        float w0 = (float)__builtin_bit_cast(_Float16, (ushort)(WIDX ? (e0.y >> 16) : (e0.y & 0xFFFFu)));
        float w1 = (float)__builtin_bit_cast(_Float16, (ushort)(WIDX ? (e1.y >> 16) : (e1.y & 0xFFFFu)));
        float w2 = (float)__builtin_bit_cast(_Float16, (ushort)(WIDX ? (e2.y >> 16) : (e2.y & 0xFFFFu)));
        float w3 = (float)__builtin_bit_cast(_Float16, (ushort)(WIDX ? (e3.y >> 16) : (e3.y & 0xFFFFu)));
        const f16x8 v0 = *reinterpret_cast<const f16x8*>(&xh[(long)e0.x * D + dl * 8]);
        const f16x8 v1 = *reinterpret_cast<const f16x8*>(&xh[(long)e1.x * D + dl * 8]);
        const f16x8 v2 = *reinterpret_cast<const f16x8*>(&xh[(long)e2.x * D + dl * 8]);
        const f16x8 v3 = *reinterpret_cast<const f16x8*>(&xh[(long)e3.x * D + dl * 8]);
#pragma unroll
        for (int j = 0; j < 8; ++j)
            a[j] += (float)v0[j] * w0 + (float)v1[j] * w1
                  + (float)v2[j] * w2 + (float)v3[j] * w3;
    }
    for (; i + 7 < end; i += 8) {
        const uint2 e0 = edges[i + par];
        const uint2 e1 = edges[i + 4 + par];
        float w0 = (float)__builtin_bit_cast(_Float16, (ushort)(WIDX ? (e0.y >> 16) : (e0.y & 0xFFFFu)));
        float w1 = (float)__builtin_bit_cast(_Float16, (ushort)(WIDX ? (e1.y >> 16) : (e1.y & 0xFFFFu)));
        const f16x8 v0 = *reinterpret_cast<const f16x8*>(&xh[(long)e0.x * D + dl * 8]);
        const f16x8 v1 = *reinterpret_cast<const f16x8*>(&xh[(long)e1.x * D + dl * 8]);
#pragma unroll
        for (int j = 0; j < 8; ++j)
            a[j] += (float)v0[j] * w0 + (float)v1[j] * w1;
    }
    for (; i < end; i += 4) {
        int idx = i + par;
        bool act = idx < end;
        const uint2 e0 = edges[act ? idx : end - 1];
        float w0 = act ? (float)__builtin_bit_cast(_Float16, (ushort)(WIDX ? (e0.y >> 16) : (e0.y & 0xFFFFu))) : 0.f;
        const f16x8 v0 = *reinterpret_cast<const f16x8*>(&xh[(long)e0.x * D + dl * 8]);
#pragma unroll
        for (int j = 0; j < 8; ++j)
            a[j] += (float)v0[j] * w0;
    }

#pragma unroll
    for (int j = 0; j < 8; ++j) {
        a[j] += __shfl_xor(a[j], 16, 64);
        a[j] += __shfl_xor(a[j], 32, 64);
    }

    if (par == 0) {
        ushort4 r0, r1;
        float v;
        v = a[0]; v = v > 0.f ? v : 0.01f * v; r0.x = f2h(v);
        v = a[1]; v = v > 0.f ? v : 0.01f * v; r0.y = f2h(v);
        v = a[2]; v = v > 0.f ? v : 0.01f * v; r0.z = f2h(v);
        v = a[3]; v = v > 0.f ? v : 0.01f * v; r0.w = f2h(v);
        v = a[4]; v = v > 0.f ? v : 0.01f * v; r1.x = f2h(v);
        v = a[5]; v = v > 0.f ? v : 0.01f * v; r1.y = f2h(v);
        v = a[6]; v = v > 0.f ? v : 0.01f * v; r1.z = f2h(v);
        v = a[7]; v = v > 0.f ? v : 0.01f * v; r1.w = f2h(v);
        *reinterpret_cast<ushort4*>(&out[(long)n * D + dl * 8]) = r0;
        *reinterpret_cast<ushort4*>(&out[(long)n * D + dl * 8 + 4]) = r1;
    }
}

// ---------------- MFMA fp16 GEMM with LDS-staged W ----------------
// 512 threads = 8 waves x 16 rows = 128 rows/block. W (64 KB) staged in LDS once;
// B-frags via ds_read_b128 (conflict-free). A-frags from global.

#define WSH (2 * D * D)   // 32768 shorts = 64 KB

__global__ __launch_bounds__(512) void gemm_mfma_kernel(
        const ushort* __restrict__ in1,
        const ushort* __restrict__ in2,
        const ushort* __restrict__ Wt,
        const float* __restrict__ bias,
        ushort* __restrict__ outp) {
    __shared__ __align__(16) ushort lds_w[WSH];
    int tid = threadIdx.x;
#pragma unroll
    for (int it = 0; it < 8; ++it) {
        int idx = it * 512 + tid;
        *reinterpret_cast<f16x8*>(&lds_w[idx * 8]) =
            *reinterpret_cast<const f16x8*>(&Wt[idx * 8]);
    }
    __syncthreads();

    int w = tid >> 6, l = tid & 63;
    int c = l & 15, kg = l >> 4;
    int base_m = blockIdx.x * 128 + w * 16;
    int r0 = base_m + c;  if (r0 >= N_NODES) r0 = N_NODES - 1;

    f32x4 acc[8];
#pragma unroll
    for (int ni = 0; ni < 8; ++ni) acc[ni] = (f32x4)0.f;

    for (int ks = 0; ks < 8; ++ks) {
        int kb = (ks & 3) * 32 + kg * 8;
        const ushort* src = (ks < 4) ? in1 : in2;
        f16x8 a0 = *reinterpret_cast<const f16x8*>(&src[(long)r0 * D + kb]);
        const ushort* wb = &lds_w[(size_t)((ks * 4 + kg) * 128) * 8];
#pragma unroll
        for (int ni = 0; ni < 8; ++ni) {
            const f16x8 b = *reinterpret_cast<const f16x8*>(&wb[(ni * 16 + c) * 8]);
            acc[ni] = __builtin_amdgcn_mfma_f32_16x16x32_f16(a0, b, acc[ni], 0, 0, 0);
        }
    }

    float bv[8];
#pragma unroll
    for (int ni = 0; ni < 8; ++ni) bv[ni] = bias[ni * 16 + c];
    int rowb = base_m + kg * 4;
#pragma unroll
    for (int r = 0; r < 4; ++r) {
        int row = rowb + r;
        if (row < N_NODES) {
#pragma unroll
            for (int ni = 0; ni < 8; ++ni) {
                float v = acc[ni][r] + bv[ni];
                v = v > 0.f ? v : 0.f;
                outp[(long)row * D + ni * 16 + c] = f2h(v);
            }
        }
    }
}

// ---------------- Fused layer-2 GEMM + classifier (LDS-staged W2) ----------
// Phase A: h2 = relu([h1|A] @ W2 + b2), B-frags from LDS.
// h2 tile overlays the consumed W2 LDS region. Phase B: Wl1t from global.

#define LSTR 136   // h2 LDS row stride in shorts

__global__ __launch_bounds__(512) void gemm2_cls_kernel(
        const ushort* __restrict__ in1,
        const ushort* __restrict__ in2,
        const ushort* __restrict__ W2t,
        const float* __restrict__ b2,
        const ushort* __restrict__ Wl1t,
        const float* __restrict__ bl1,
        const float* __restrict__ Wl2,
        const float* __restrict__ bl2,
        float* __restrict__ out) {
    __shared__ __align__(16) ushort lds_w[WSH];
    int tid = threadIdx.x;
#pragma unroll
    for (int it = 0; it < 8; ++it) {
        int idx = it * 512 + tid;
        *reinterpret_cast<f16x8*>(&lds_w[idx * 8]) =
            *reinterpret_cast<const f16x8*>(&W2t[idx * 8]);
    }
    __syncthreads();

    int w = tid >> 6, l = tid & 63;
    int c = l & 15, kg = l >> 4;
    int base_m = blockIdx.x * 128 + w * 16;
    int r0 = base_m + c;  if (r0 >= N_NODES) r0 = N_NODES - 1;

    // ---- phase A ----
    f32x4 acc[8];
#pragma unroll
    for (int ni = 0; ni < 8; ++ni) acc[ni] = (f32x4)0.f;

    for (int ks = 0; ks < 8; ++ks) {
        int kb = (ks & 3) * 32 + kg * 8;
        const ushort* src = (ks < 4) ? in1 : in2;
        f16x8 a0 = *reinterpret_cast<const f16x8*>(&src[(long)r0 * D + kb]);
        const ushort* wb = &lds_w[(size_t)((ks * 4 + kg) * 128) * 8];
#pragma unroll
        for (int ni = 0; ni < 8; ++ni) {
            const f16x8 b = *reinterpret_cast<const f16x8*>(&wb[(ni * 16 + c) * 8]);
            acc[ni] = __builtin_amdgcn_mfma_f32_16x16x32_f16(a0, b, acc[ni], 0, 0, 0);
        }
    }

    float bv[8];
#pragma unroll
    for (int ni = 0; ni < 8; ++ni) bv[ni] = b2[ni * 16 + c];

    __syncthreads();   // all waves done reading W2 from LDS
    // h2 tile overlays lds_w: wave w rows at lds_w[w*16*LSTR ...]
    ushort* h2 = &lds_w[w * 16 * LSTR];
#pragma unroll
    for (int r = 0; r < 4; ++r) {
        int lrow = kg * 4 + r;
#pragma unroll
        for (int ni = 0; ni < 8; ++ni) {
            float v = acc[ni][r] + bv[ni];
            v = v > 0.f ? v : 0.f;
            h2[lrow * LSTR + ni * 16 + c] = f2h(v);
        }
    }
    __syncthreads();

    // ---- phase B: classifier ----
    f32x4 bcc[8];
#pragma unroll
    for (int ni = 0; ni < 8; ++ni) bcc[ni] = (f32x4)0.f;

    for (int ks = 0; ks < 4; ++ks) {
        int kb = ks * 32 + kg * 8;
        f16x8 a0 = *reinterpret_cast<const f16x8*>(&h2[c * LSTR + kb]);
        const ushort* wb = &Wl1t[(size_t)((ks * 4 + kg) * 128) * 8];
#pragma unroll
        for (int ni = 0; ni < 8; ++ni) {
            const f16x8 b = *reinterpret_cast<const f16x8*>(&wb[(ni * 16 + c) * 8]);
            bcc[ni] = __builtin_amdgcn_mfma_f32_16x16x32_f16(a0, b, bcc[ni], 0, 0, 0);
        }
    }

    float b1v[8]; float2 w2v[8];
#pragma unroll
    for (int ni = 0; ni < 8; ++ni) {
        b1v[ni] = bl1[ni * 16 + c];
        w2v[ni] = *reinterpret_cast<const float2*>(&Wl2[(ni * 16 + c) * 2]);
    }
    float p0[4] = {0.f, 0.f, 0.f, 0.f};
    float p1[4] = {0.f, 0.f, 0.f, 0.f};
#pragma unroll
    for (int ni = 0; ni < 8; ++ni) {
#pragma unroll
        for (int r = 0; r < 4; ++r) {
            float t = bcc[ni][r] + b1v[ni];
            t = t > 0.f ? t : 0.f;
            p0[r] += t * w2v[ni].x;
            p1[r] += t * w2v[ni].y;
        }
    }
#pragma unroll
    for (int r = 0; r < 4; ++r) {
#pragma unroll
        for (int m = 1; m < 16; m <<= 1) {
            p0[r] += __shfl_xor(p0[r], m, 64);
            p1[r] += __shfl_xor(p1[r], m, 64);
        }
    }
    if (c < 2) {
        int rowb = base_m + kg * 4;
#pragma unroll
        for (int r = 0; r < 4; ++r) {
            int row = rowb + r;
            if (row < N_NODES)
                out[(long)row * 2 + c] = (c == 0 ? p0[r] : p1[r]) + bl2[c];
        }
    }
}

// ---------------- launch ----------------

extern "C" void kernel_launch(void* const* d_in, const int* in_sizes, int n_in,
                              void* d_out, int out_size, void* d_ws, size_t ws_size,
                              hipStream_t stream) {
    const float* x   = (const float*)d_in[0];
    const int* esrc  = (const int*)d_in[1];
    const int* edst  = (const int*)d_in[2];
    const float* ew1 = (const float*)d_in[3];
    const float* ew2 = (const float*)d_in[4];
    const float* W1  = (const float*)d_in[5];
    const float* b1  = (const float*)d_in[6];
    const float* W2  = (const float*)d_in[7];
    const float* b2  = (const float*)d_in[8];
    const float* Wl1 = (const float*)d_in[9];
    const float* bl1 = (const float*)d_in[10];
    const float* Wl2 = (const float*)d_in[11];
    const float* bl2 = (const float*)d_in[12];
    float* out = (float*)d_out;

    char* p = (char*)d_ws;
    ushort* Af      = (ushort*)p;          p += (size_t)N_NODES * D * 2;   // agg (fp16)
    ushort* h1f     = (ushort*)p;          p += (size_t)N_NODES * D * 2;   // h1 (fp16)
    ushort* xf      = (ushort*)p;          p += (size_t)N_NODES * D * 2;   // x (fp16)
    int* row_ptr    = (int*)p;             p += (size_t)(N_NODES + 16) * 4;
    int* blockhist  = (int*)p;             p += (size_t)SCAN_TOT * 4;      // 307 KB
    int* partials   = (int*)p;             p += 128 * 4;
    uint2* part     = (uint2*)p;           p += (size_t)N_EDGES * 8;       // 12.8 MB
    uint2* packed   = (uint2*)p;           p += (size_t)N_EDGES * 8;       // 12.8 MB
    ushort* W1t     = (ushort*)p;          p += 2 * D * D * 2;
    ushort* W2t     = (ushort*)p;          p += 2 * D * D * 2;
    ushort* Wl1t    = (ushort*)p;          p += D * D * 2;

    // prep: histogram + W tiling + x convert in one launch (independent work)
    prep_kernel<<<NCHUNK + WT_BLK + CVT_BLK, 256, 0, stream>>>(
        edst, blockhist, W1, W2, Wl1, W1t, W2t, Wl1t, x, xf);
    scan_a<<<SC_NB, 256, 0, stream>>>(blockhist, partials);
    scan_c<<<SC_NB, 256, 0, stream>>>(blockhist, partials, row_ptr);
    p1_scatter<<<NCHUNK, 256, 0, stream>>>(esrc, edst, ew1, ew2, blockhist, part);
    p2_kernel<<<NBIN, 256, 0, stream>>>(blockhist, part, row_ptr, packed);

    int ggrid = (N_NODES + 127) / 128;   // 782 (512-thread blocks)

    // layer 1
    spmm_kernel<0><<<N_NODES / 4, 256, 0, stream>>>(xf, packed, row_ptr, Af);
    gemm_mfma_kernel<<<ggrid, 512, 0, stream>>>(xf, Af, W1t, b1, h1f);
    // layer 2 + classifier fused (h2 never touches global memory)
    spmm_kernel<1><<<N_NODES / 4, 256, 0, stream>>>(h1f, packed, row_ptr, Af);
    gemm2_cls_kernel<<<ggrid, 512, 0, stream>>>(h1f, Af, W2t, b2, Wl1t, bl1, Wl2, bl2, out);
}